// Round 8
// baseline (143771.021 us; speedup 1.0000x reference)
//
#include <hip/hip_runtime.h>

// Echo-state network recurrence on MI355X (gfx950).
// Round-8: round-3 skeleton (known-good, 87 ms) + `nt` poll loads.
// Evidence: FETCH_SIZE=46KB/step (8KB x ~6 XCDs) proves sc1 polls hit local
// L2 with invalidate-on-store sharing -> consumers spin on valid-STALE lines
// until cross-XCD invalidation propagates (hidden serial cost every step).
// `sc1 nt` polls never allocate in L2 -> every spin iteration reads the MALL
// directly -> first poll after producer write-through sees fresh data, no
// invalidation dependency. Tags self-validate => correctness-neutral.
// Rounds 6/7 post-mortem: sc0-alone = SE scope (SC[1:0]=01) -> stale-L1/L2
// spins -> hang; single-XCD plan abandoned.

#define HH   1024
#define TT   50000
#define WASH 200
#define NWG  128
#define NT   64

typedef unsigned int u32;
typedef unsigned long long u64;
typedef u32 u32x4 __attribute__((ext_vector_type(4)));

__device__ __forceinline__ float fast_tanh(float x) {
  // tanh(x) = 1 - 2/(exp2(2x*log2e)+1); safe at +/-inf.
  float e = __builtin_amdgcn_exp2f(x * 2.8853900817779268f);
  return fmaf(-2.0f, __builtin_amdgcn_rcpf(e + 1.0f), 1.0f);
}

template <int CTRL>
__device__ __forceinline__ float dpp_movf(float x) {
  return __int_as_float(__builtin_amdgcn_update_dpp(
      0, __float_as_int(x), CTRL, 0xF, 0xF, true));
}
__device__ __forceinline__ float swz_xor16(float x) {
  return __int_as_float(__builtin_amdgcn_ds_swizzle(__float_as_int(x), 0x401F));
}

// 8 batched device-scope NON-TEMPORAL 16B loads covering all 1024 pairs.
// Load k covers state cols {128k+2l, 128k+2l+1} for lane l.
#define POLL_ISSUE(bA, bB)                                                               \
  asm volatile("global_load_dwordx4 %0, %1, off sc1 nt"             : "=v"(pr0) : "v"(bA)); \
  asm volatile("global_load_dwordx4 %0, %1, off offset:1024 sc1 nt" : "=v"(pr1) : "v"(bA)); \
  asm volatile("global_load_dwordx4 %0, %1, off offset:2048 sc1 nt" : "=v"(pr2) : "v"(bA)); \
  asm volatile("global_load_dwordx4 %0, %1, off offset:3072 sc1 nt" : "=v"(pr3) : "v"(bA)); \
  asm volatile("global_load_dwordx4 %0, %1, off sc1 nt"             : "=v"(pr4) : "v"(bB)); \
  asm volatile("global_load_dwordx4 %0, %1, off offset:1024 sc1 nt" : "=v"(pr5) : "v"(bB)); \
  asm volatile("global_load_dwordx4 %0, %1, off offset:2048 sc1 nt" : "=v"(pr6) : "v"(bB)); \
  asm volatile("global_load_dwordx4 %0, %1, off offset:3072 sc1 nt" : "=v"(pr7) : "v"(bB))

#define POLL_WAIT0()                                                      \
  asm volatile("s_waitcnt vmcnt(0)"                                       \
               : "+v"(pr0), "+v"(pr1), "+v"(pr2), "+v"(pr3),              \
                 "+v"(pr4), "+v"(pr5), "+v"(pr6), "+v"(pr7))

#define TAGBAD(n) ((pr##n.y ^ want) | (pr##n.w ^ want))
#define TAGBAD_ALL                                                        \
  (TAGBAD(0) | TAGBAD(1) | TAGBAD(2) | TAGBAD(3) |                        \
   TAGBAD(4) | TAGBAD(5) | TAGBAD(6) | TAGBAD(7))

#define FMA_K(k)                                                            \
  { float xa = __uint_as_float(pr##k.x);                                    \
    float xb = __uint_as_float(pr##k.z);                                    \
    acc0 = fmaf(wr[0][2*k], xa, acc0); acc0 = fmaf(wr[0][2*k+1], xb, acc0); \
    acc1 = fmaf(wr[1][2*k], xa, acc1); acc1 = fmaf(wr[1][2*k+1], xb, acc1); \
    acc2 = fmaf(wr[2][2*k], xa, acc2); acc2 = fmaf(wr[2][2*k+1], xb, acc2); \
    acc3 = fmaf(wr[3][2*k], xa, acc3); acc3 = fmaf(wr[3][2*k+1], xb, acc3); \
    acc4 = fmaf(wr[4][2*k], xa, acc4); acc4 = fmaf(wr[4][2*k+1], xb, acc4); \
    acc5 = fmaf(wr[5][2*k], xa, acc5); acc5 = fmaf(wr[5][2*k+1], xb, acc5); \
    acc6 = fmaf(wr[6][2*k], xa, acc6); acc6 = fmaf(wr[6][2*k+1], xb, acc6); \
    acc7 = fmaf(wr[7][2*k], xa, acc7); acc7 = fmaf(wr[7][2*k+1], xb, acc7); }
#define FMA_ALL                                                           \
  { FMA_K(0); FMA_K(1); FMA_K(2); FMA_K(3);                               \
    FMA_K(4); FMA_K(5); FMA_K(6); FMA_K(7); }

#define RD_K(k)                                                           \
  { y = fmaf(cr[2*k],   __uint_as_float(pr##k.x), y);                     \
    y = fmaf(cr[2*k+1], __uint_as_float(pr##k.z), y); }
#define RD_ALL                                                            \
  { RD_K(0); RD_K(1); RD_K(2); RD_K(3);                                   \
    RD_K(4); RD_K(5); RD_K(6); RD_K(7); }

#define YREDUCE()                                                         \
  { y += __shfl_xor(y, 32);                                               \
    y += swz_xor16(y);                                                    \
    y += dpp_movf<0x128>(y);   /* row_ror:8   */                          \
    y += dpp_movf<0x141>(y);   /* half mirror */                          \
    y += dpp_movf<0x1B>(y);    /* quad reverse*/                          \
    y += dpp_movf<0xB1>(y); }  /* quad xor1   */

__global__ __launch_bounds__(NT, 1) void esn_kernel(
    const float* __restrict__ u,
    const float* __restrict__ w_in,
    const float* __restrict__ w_res,
    const float* __restrict__ w_out,
    const int*   __restrict__ mask,
    float*       __restrict__ out,
    u64*         __restrict__ xws)   // 2 * HH tagged pairs (16 KiB)
{
  const int w = blockIdx.x;    // owns rows [8w, 8w+8)
  const int l = threadIdx.x;   // lane; cols {128k+2l, 128k+2l+1 : k in [0,8)}

  __shared__ float lds_c[HH];
  for (int h = l; h < HH; h += NT) lds_c[mask[h]] = w_out[h];
  __syncthreads();

  // weights resident in registers: 8 rows x 16 cols per lane
  float wr[8][16];
#pragma unroll
  for (int r = 0; r < 8; ++r) {
    const float2* wp = (const float2*)(w_res + (size_t)(8 * w + r) * HH) + l;
#pragma unroll
    for (int k = 0; k < 8; ++k) {
      float2 v = wp[64 * k];
      wr[r][2 * k] = v.x; wr[r][2 * k + 1] = v.y;
    }
  }

  const float win = w_in[8 * w + (l >> 3)];  // lane (l&7)==0 stores row 8w+(l>>3)

  float cr[16];                              // readout coeffs (all WGs)
#pragma unroll
  for (int k = 0; k < 8; ++k) {
    float2 v = ((const float2*)lds_c)[64 * k + l];
    cr[2 * k] = v.x; cr[2 * k + 1] = v.y;
  }

  u64* xb0 = xws;        // parity-0 buffer (x_t for even t)
  u64* xb1 = xws + HH;   // parity-1 buffer
  const u64* pA0 = xb0 + 2 * l;
  const u64* pB0 = pA0 + 512;
  const u64* pA1 = xb1 + 2 * l;
  const u64* pB1 = pA1 + 512;
  const int drow = 8 * w + (l >> 3);
  u64* d0 = xb0 + drow;
  u64* d1 = xb1 + drow;

  u32x4 pr0, pr1, pr2, pr3, pr4, pr5, pr6, pr7;
  const int lb32 = l & 32, lb16 = l & 16, lb8 = l & 8;

  for (int t = 0; t < TT; ++t) {
    const int pa = t & 1;
    const float u_t = u[t];
    float acc0 = 0.f, acc1 = 0.f, acc2 = 0.f, acc3 = 0.f;
    float acc4 = 0.f, acc5 = 0.f, acc6 = 0.f, acc7 = 0.f;
    const bool doRead = ((t & 127) == w) && (t > 0);
    float y = 0.f;

    if (t > 0) {
      const u64* bA = pa ? pA0 : pA1;   // source = buf[(t-1)&1]
      const u64* bB = pa ? pB0 : pB1;
      const u32 want = (u32)t;          // tag of x_{t-1}
      for (;;) {
        POLL_ISSUE(bA, bB);
        POLL_WAIT0();
        if (!TAGBAD_ALL) break;
      }
      FMA_ALL;
      if (doRead) RD_ALL;
    }

    // fold 64 lanes x 8 accs -> row (l>>3) sum on lanes with (l&7)==0
    float t0 = (lb32 ? acc4 : acc0) + __shfl_xor(lb32 ? acc0 : acc4, 32);
    float t1 = (lb32 ? acc5 : acc1) + __shfl_xor(lb32 ? acc1 : acc5, 32);
    float t2 = (lb32 ? acc6 : acc2) + __shfl_xor(lb32 ? acc2 : acc6, 32);
    float t3 = (lb32 ? acc7 : acc3) + __shfl_xor(lb32 ? acc3 : acc7, 32);
    float s0 = (lb16 ? t2 : t0) + swz_xor16(lb16 ? t0 : t2);
    float s1 = (lb16 ? t3 : t1) + swz_xor16(lb16 ? t1 : t3);
    float r0 = (lb8 ? s1 : s0) + dpp_movf<0x128>(lb8 ? s0 : s1);
    r0 += dpp_movf<0x141>(r0);
    r0 += dpp_movf<0x1B>(r0);
    r0 += dpp_movf<0xB1>(r0);

    float x_new = fast_tanh(fmaf(win, u_t, r0));
    u64 packed = ((u64)(u32)(t + 1) << 32) | __float_as_uint(x_new);
    if ((l & 7) == 0) {
      u64* dst = pa ? d1 : d0;          // x_t -> buf[t&1]
      asm volatile("global_store_dwordx2 %0, %1, off sc1"
                   :: "v"(dst), "v"(packed));
    }

    // readout y_{t-1} (this WG's turn; after the store, off critical path)
    if (doRead) {
      YREDUCE();
      if (l == 0 && t - 1 >= WASH) out[t - 1 - WASH] = y;
    }
  }

  // final readout: x_{TT-1} stored but never polled in-loop (WG 0, one-time)
  if (w == 0) {
    const u32 want = (u32)TT;           // x_{TT-1} lives in buf[(TT-1)&1]=buf[1]
    for (;;) {
      POLL_ISSUE(pA1, pB1);
      POLL_WAIT0();
      if (!TAGBAD_ALL) break;
    }
    float y = 0.f;
    RD_ALL;
    YREDUCE();
    if (l == 0) out[TT - 1 - WASH] = y;
  }
}

extern "C" void kernel_launch(void* const* d_in, const int* in_sizes, int n_in,
                              void* d_out, int out_size, void* d_ws, size_t ws_size,
                              hipStream_t stream) {
  const float* u     = (const float*)d_in[0];
  const float* w_in  = (const float*)d_in[1];
  const float* w_res = (const float*)d_in[2];
  const float* w_out = (const float*)d_in[3];
  const int*   mask  = (const int*)d_in[4];
  float* out = (float*)d_out;

  esn_kernel<<<NWG, NT, 0, stream>>>(u, w_in, w_res, w_out, mask, out,
                                     (u64*)d_ws);
}

// Round 9
// 63529.163 us; speedup vs baseline: 2.2631x; 2.2631x over previous
//
#include <hip/hip_runtime.h>

// Echo-state network recurrence on MI355X (gfx950).
// Round-9: single-XCD team with CORRECTED cache scopes.
// Evidence chain: cross-XCD sync floor ~4000 cyc/step (r3); nt-polls prove
// L2-hit polling + pushed invalidation is optimal transport given cross-XCD
// (r8); r6/7 hangs were sc0(=SE scope) polls served by stale L1.
// Design: all 128 participant waves claim roles on XCD 0; producers publish
// with PLAIN stores (write-through L1 -> dirty in XCD0's shared L2, no MALL
// trip); consumers poll with sc1 (L1-bypass, L2-hit allowed -> sees dirty
// line). Tagged (value,tag) pairs self-validate. All spins bounded + dead-
// latch: any failure terminates with wrong output instead of hanging.

#define HH   1024
#define TT   50000
#define WASH 200
#define NROLE 128   // role w owns rows [8w, 8w+8)
#define NBLK  2048
#define NT    64
#define SPIN_CAP (1u << 20)

typedef unsigned int u32;
typedef unsigned long long u64;
typedef u32 u32x4 __attribute__((ext_vector_type(4)));

__device__ __forceinline__ float fast_tanh(float x) {
  // tanh(x) = 1 - 2/(exp2(2x*log2e)+1); safe at +/-inf.
  float e = __builtin_amdgcn_exp2f(x * 2.8853900817779268f);
  return fmaf(-2.0f, __builtin_amdgcn_rcpf(e + 1.0f), 1.0f);
}

template <int CTRL>
__device__ __forceinline__ float dpp_movf(float x) {
  return __int_as_float(__builtin_amdgcn_update_dpp(
      0, __float_as_int(x), CTRL, 0xF, 0xF, true));
}
__device__ __forceinline__ float swz_xor16(float x) {
  return __int_as_float(__builtin_amdgcn_ds_swizzle(__float_as_int(x), 0x401F));
}

// 8 batched 16B poll loads (sc1: L1-bypass, may hit the shared XCD L2).
#define POLL_ISSUE(bA, bB)                                                            \
  asm volatile("global_load_dwordx4 %0, %1, off sc1"             : "=v"(pr0) : "v"(bA)); \
  asm volatile("global_load_dwordx4 %0, %1, off offset:1024 sc1" : "=v"(pr1) : "v"(bA)); \
  asm volatile("global_load_dwordx4 %0, %1, off offset:2048 sc1" : "=v"(pr2) : "v"(bA)); \
  asm volatile("global_load_dwordx4 %0, %1, off offset:3072 sc1" : "=v"(pr3) : "v"(bA)); \
  asm volatile("global_load_dwordx4 %0, %1, off sc1"             : "=v"(pr4) : "v"(bB)); \
  asm volatile("global_load_dwordx4 %0, %1, off offset:1024 sc1" : "=v"(pr5) : "v"(bB)); \
  asm volatile("global_load_dwordx4 %0, %1, off offset:2048 sc1" : "=v"(pr6) : "v"(bB)); \
  asm volatile("global_load_dwordx4 %0, %1, off offset:3072 sc1" : "=v"(pr7) : "v"(bB))

#define POLL_WAIT0()                                                      \
  asm volatile("s_waitcnt vmcnt(0)"                                       \
               : "+v"(pr0), "+v"(pr1), "+v"(pr2), "+v"(pr3),              \
                 "+v"(pr4), "+v"(pr5), "+v"(pr6), "+v"(pr7))

#define TAGBAD(n) ((pr##n.y ^ want) | (pr##n.w ^ want))
#define TAGBAD_ALL                                                        \
  (TAGBAD(0) | TAGBAD(1) | TAGBAD(2) | TAGBAD(3) |                        \
   TAGBAD(4) | TAGBAD(5) | TAGBAD(6) | TAGBAD(7))

#define FMA_K(k)                                                            \
  { float xa = __uint_as_float(pr##k.x);                                    \
    float xb = __uint_as_float(pr##k.z);                                    \
    acc0 = fmaf(wr[0][2*k], xa, acc0); acc0 = fmaf(wr[0][2*k+1], xb, acc0); \
    acc1 = fmaf(wr[1][2*k], xa, acc1); acc1 = fmaf(wr[1][2*k+1], xb, acc1); \
    acc2 = fmaf(wr[2][2*k], xa, acc2); acc2 = fmaf(wr[2][2*k+1], xb, acc2); \
    acc3 = fmaf(wr[3][2*k], xa, acc3); acc3 = fmaf(wr[3][2*k+1], xb, acc3); \
    acc4 = fmaf(wr[4][2*k], xa, acc4); acc4 = fmaf(wr[4][2*k+1], xb, acc4); \
    acc5 = fmaf(wr[5][2*k], xa, acc5); acc5 = fmaf(wr[5][2*k+1], xb, acc5); \
    acc6 = fmaf(wr[6][2*k], xa, acc6); acc6 = fmaf(wr[6][2*k+1], xb, acc6); \
    acc7 = fmaf(wr[7][2*k], xa, acc7); acc7 = fmaf(wr[7][2*k+1], xb, acc7); }
#define FMA_ALL                                                           \
  { FMA_K(0); FMA_K(1); FMA_K(2); FMA_K(3);                               \
    FMA_K(4); FMA_K(5); FMA_K(6); FMA_K(7); }

#define RD_K(k)                                                           \
  { y = fmaf(cr[2*k],   __uint_as_float(pr##k.x), y);                     \
    y = fmaf(cr[2*k+1], __uint_as_float(pr##k.z), y); }
#define RD_ALL                                                            \
  { RD_K(0); RD_K(1); RD_K(2); RD_K(3);                                   \
    RD_K(4); RD_K(5); RD_K(6); RD_K(7); }

#define YREDUCE()                                                         \
  { y += __shfl_xor(y, 32);                                               \
    y += swz_xor16(y);                                                    \
    y += dpp_movf<0x128>(y);   /* row_ror:8   */                          \
    y += dpp_movf<0x141>(y);   /* half mirror */                          \
    y += dpp_movf<0x1B>(y);    /* quad reverse*/                          \
    y += dpp_movf<0xB1>(y); }  /* quad xor1   */

__global__ __launch_bounds__(NT, 2) void esn_kernel(
    const float* __restrict__ u,
    const float* __restrict__ w_in,
    const float* __restrict__ w_res,
    const float* __restrict__ w_out,
    const int*   __restrict__ mask,
    float*       __restrict__ out,
    char*        __restrict__ ws)
{
  const int l = threadIdx.x;

  // --- team formation: XCD 0 only, first 128 claimants persist ---
  u32 xcc;
  asm("s_getreg_b32 %0, hwreg(HW_REG_XCC_ID)" : "=s"(xcc));
  if (xcc != 0) return;
  int slot = 0;
  if (l == 0) slot = atomicAdd((int*)ws, 1);   // ws[0..63] zeroed each launch
  slot = __shfl(slot, 0);
  if (slot >= NROLE) return;
  const int w = slot;                          // role: rows [8w, 8w+8)

  u64* xb0 = (u64*)(ws + 4096);        // parity-0 tagged buffer (8 KB)
  u64* xb1 = xb0 + HH;                 // parity-1 tagged buffer

  __shared__ float lds_c[HH];
  for (int h = l; h < HH; h += NT) lds_c[mask[h]] = w_out[h];
  __syncthreads();

  // weights resident in registers: 8 rows x 16 cols per lane
  float wr[8][16];
#pragma unroll
  for (int r = 0; r < 8; ++r) {
    const float2* wp = (const float2*)(w_res + (size_t)(8 * w + r) * HH) + l;
#pragma unroll
    for (int k = 0; k < 8; ++k) {
      float2 v = wp[64 * k];
      wr[r][2 * k] = v.x; wr[r][2 * k + 1] = v.y;
    }
  }

  const float win = w_in[8 * w + (l >> 3)];  // lane (l&7)==0 stores row 8w+(l>>3)

  float cr[16];
#pragma unroll
  for (int k = 0; k < 8; ++k) {
    float2 v = ((const float2*)lds_c)[64 * k + l];
    cr[2 * k] = v.x; cr[2 * k + 1] = v.y;
  }

  const u64* pA0 = xb0 + 2 * l;
  const u64* pB0 = pA0 + 512;
  const u64* pA1 = xb1 + 2 * l;
  const u64* pB1 = pA1 + 512;
  const int drow = 8 * w + (l >> 3);
  u64* d0 = xb0 + drow;
  u64* d1 = xb1 + drow;

  u32x4 pr0, pr1, pr2, pr3, pr4, pr5, pr6, pr7;
  const int lb32 = l & 32, lb16 = l & 16, lb8 = l & 8;
  int dead = 0;   // latched on spin-cap trip: free-run to termination

  for (int t = 0; t < TT; ++t) {
    const int pa = t & 1;
    const float u_t = u[t];
    float acc0 = 0.f, acc1 = 0.f, acc2 = 0.f, acc3 = 0.f;
    float acc4 = 0.f, acc5 = 0.f, acc6 = 0.f, acc7 = 0.f;
    const bool doRead = ((t & 127) == w) && (t > 0);
    float y = 0.f;

    if (t > 0 && !dead) {
      const u64* bA = pa ? pA0 : pA1;   // source = buf[(t-1)&1]
      const u64* bB = pa ? pB0 : pB1;
      const u32 want = (u32)t;          // tag of x_{t-1}
      u32 guard = 0;
      for (;;) {
        POLL_ISSUE(bA, bB);
        POLL_WAIT0();
        if (!TAGBAD_ALL) break;
        if (++guard > SPIN_CAP) { dead = 1; break; }
      }
      FMA_ALL;
      if (doRead) RD_ALL;
    }

    // fold 64 lanes x 8 accs -> row (l>>3) sum on lanes with (l&7)==0
    float t0 = (lb32 ? acc4 : acc0) + __shfl_xor(lb32 ? acc0 : acc4, 32);
    float t1 = (lb32 ? acc5 : acc1) + __shfl_xor(lb32 ? acc1 : acc5, 32);
    float t2 = (lb32 ? acc6 : acc2) + __shfl_xor(lb32 ? acc2 : acc6, 32);
    float t3 = (lb32 ? acc7 : acc3) + __shfl_xor(lb32 ? acc3 : acc7, 32);
    float s0 = (lb16 ? t2 : t0) + swz_xor16(lb16 ? t0 : t2);
    float s1 = (lb16 ? t3 : t1) + swz_xor16(lb16 ? t1 : t3);
    float r0 = (lb8 ? s1 : s0) + dpp_movf<0x128>(lb8 ? s0 : s1);
    r0 += dpp_movf<0x141>(r0);
    r0 += dpp_movf<0x1B>(r0);
    r0 += dpp_movf<0xB1>(r0);

    float x_new = fast_tanh(fmaf(win, u_t, r0));
    u64 packed = ((u64)(u32)(t + 1) << 32) | __float_as_uint(x_new);
    if ((l & 7) == 0) {
      u64* dst = pa ? d1 : d0;          // x_t -> buf[t&1]
      // PLAIN store: write-through L1 -> dirty in XCD0's shared L2.
      asm volatile("global_store_dwordx2 %0, %1, off"
                   :: "v"(dst), "v"(packed));
    }

    // readout y_{t-1} (this role's turn; after the store, off critical path)
    if (doRead) {
      YREDUCE();
      if (l == 0 && t - 1 >= WASH) out[t - 1 - WASH] = y;
    }
  }

  // final readout: x_{TT-1} stored but never polled in-loop (role 0)
  if (w == 0) {
    const u32 want = (u32)TT;           // x_{TT-1} lives in buf[(TT-1)&1]=buf[1]
    u32 guard = 0;
    for (;;) {
      POLL_ISSUE(pA1, pB1);
      POLL_WAIT0();
      if (!TAGBAD_ALL) break;
      if (++guard > SPIN_CAP) break;
    }
    float y = 0.f;
    RD_ALL;
    YREDUCE();
    if (l == 0) out[TT - 1 - WASH] = y;
  }
}

extern "C" void kernel_launch(void* const* d_in, const int* in_sizes, int n_in,
                              void* d_out, int out_size, void* d_ws, size_t ws_size,
                              hipStream_t stream) {
  const float* u     = (const float*)d_in[0];
  const float* w_in  = (const float*)d_in[1];
  const float* w_res = (const float*)d_in[2];
  const float* w_out = (const float*)d_in[3];
  const int*   mask  = (const int*)d_in[4];
  float* out = (float*)d_out;

  // zero the role-claim counter; tagged buffers rely on 0xAA poison
  // (0xAAAAAAAA is never a valid tag in [1, 50001])
  hipMemsetAsync(d_ws, 0, 64, stream);

  esn_kernel<<<NBLK, NT, 0, stream>>>(u, w_in, w_res, w_out, mask, out,
                                      (char*)d_ws);
}